// Round 4
// baseline (618.789 us; speedup 1.0000x reference)
//
#include <hip/hip_runtime.h>
#include <math.h>

#define NNODES 6000
#define NEDGES 192000
#define DIN 512
#define HDIM 128
#define ALPHA 1.0f
#define EOS 1e-10f

static const size_t NN = (size_t)NNODES * (size_t)NNODES;

typedef float vfloat4 __attribute__((ext_vector_type(4)));

// ---------------------------------------------------------------------------
// Zero-fill of three ranges (adj_lp+adj_hp, unnorm/winner, deg scratch) with
// nontemporal 16B stores.  ~433 MB total -> ~70 us floor at 6.3 TB/s.
// ---------------------------------------------------------------------------
__global__ __launch_bounds__(256) void zero3_kernel(
    vfloat4* __restrict__ a, size_t na, vfloat4* __restrict__ b, size_t nb,
    vfloat4* __restrict__ c, size_t nc) {
  const size_t stride = (size_t)gridDim.x * blockDim.x;
  const size_t i = (size_t)blockIdx.x * blockDim.x + threadIdx.x;
  const vfloat4 z = {0.f, 0.f, 0.f, 0.f};
  for (size_t k = i; k < na; k += stride) __builtin_nontemporal_store(z, a + k);
  for (size_t k = i; k < nb; k += stride) __builtin_nontemporal_store(z, b + k);
  for (size_t k = i; k < nc; k += stride) c[k] = z;
}

// ---------------------------------------------------------------------------
// g[i] = dot(relu(feat[i] @ w_emb + b_emb), wv) + 0.5*b_mlp,
// wv[h] = 0.5*(w_mlp[h]+w_mlp[H+h]).  64-thread blocks, 4 nodes per block,
// thread t handles h = t and h = t+64.  Feature rows staged in LDS, read as
// float4 (ds_read_b128, 4x fewer LDS issue slots than the scalar version).
// ---------------------------------------------------------------------------
__global__ __launch_bounds__(64) void embed_g_kernel(
    const float* __restrict__ feat, const float* __restrict__ w_emb,
    const float* __restrict__ b_emb, const float* __restrict__ w_mlp,
    const float* __restrict__ b_mlp, float* __restrict__ g) {
  __shared__ float sf[4 * DIN];  // 8 KB
  const int t = threadIdx.x;     // 0..63
  const int nb = blockIdx.x * 4;

  // stage 4 feature rows: 512 float4, 8 per thread
  const float4* f4 = (const float4*)(feat + (size_t)nb * DIN);
  float4* s4 = (float4*)sf;
#pragma unroll
  for (int k = 0; k < 8; ++k) s4[k * 64 + t] = f4[k * 64 + t];
  __syncthreads();

  const int h0 = t, h1 = t + 64;
  float acc0[4], acc1[4];
  const float b0 = b_emb[h0], b1 = b_emb[h1];
#pragma unroll
  for (int n = 0; n < 4; ++n) { acc0[n] = b0; acc1[n] = b1; }

  for (int d = 0; d < DIN; d += 4) {
    float w00 = w_emb[(d + 0) * HDIM + h0];
    float w01 = w_emb[(d + 1) * HDIM + h0];
    float w02 = w_emb[(d + 2) * HDIM + h0];
    float w03 = w_emb[(d + 3) * HDIM + h0];
    float w10 = w_emb[(d + 0) * HDIM + h1];
    float w11 = w_emb[(d + 1) * HDIM + h1];
    float w12 = w_emb[(d + 2) * HDIM + h1];
    float w13 = w_emb[(d + 3) * HDIM + h1];
#pragma unroll
    for (int n = 0; n < 4; ++n) {
      const float4 f = *(const float4*)&sf[n * DIN + d];
      acc0[n] += f.x * w00;
      acc0[n] += f.y * w01;
      acc0[n] += f.z * w02;
      acc0[n] += f.w * w03;
      acc1[n] += f.x * w10;
      acc1[n] += f.y * w11;
      acc1[n] += f.z * w12;
      acc1[n] += f.w * w13;
    }
  }

  const float wv0 = 0.5f * (w_mlp[h0] + w_mlp[HDIM + h0]);
  const float wv1 = 0.5f * (w_mlp[h1] + w_mlp[HDIM + h1]);
  const float half_b = 0.5f * b_mlp[0];
#pragma unroll
  for (int n = 0; n < 4; ++n) {
    float v = fmaxf(acc0[n], 0.0f) * wv0 + fmaxf(acc1[n], 0.0f) * wv1;
#pragma unroll
    for (int off = 32; off > 0; off >>= 1) v += __shfl_down(v, off, 64);
    if (t == 0) g[nb + n] = v + half_b;  // raw = g[u]+g[v] (b_mlp folded)
  }
}

// ---------------------------------------------------------------------------
// Pass A: per-edge gate weights + last-write-wins winner via atomicMax(e+1)
// into the adj_unnorm output region (zeroed beforehand).
// ---------------------------------------------------------------------------
__global__ __launch_bounds__(256) void edge_weights_kernel(
    const int* __restrict__ edges, const float* __restrict__ g,
    const float* __restrict__ noise, float* __restrict__ w_lp,
    float* __restrict__ w_hp, int* __restrict__ winner) {
  const int e = blockIdx.x * blockDim.x + threadIdx.x;
  if (e >= NEDGES) return;
  const int u = edges[e];
  const int v = edges[NEDGES + e];
  const float x = noise[e] + g[u] + g[v];  // TEMP == 1.0, b_mlp folded in g
  const float wl = 1.0f / (1.0f + expf(-x));
  const float wh = 1.0f - wl;
  w_lp[e] = wl;
  w_hp[e] = wh;
  atomicMax(&winner[(size_t)u * NNODES + v], e + 1);
}

// ---------------------------------------------------------------------------
// Pass B: deduplicated row sums (winner edges only — numpy set semantics).
// ---------------------------------------------------------------------------
__global__ __launch_bounds__(256) void edge_deg_kernel(
    const int* __restrict__ edges, const float* __restrict__ w_lp,
    const float* __restrict__ w_hp, const int* __restrict__ winner,
    float* __restrict__ deg_lp, float* __restrict__ deg_hp) {
  const int e = blockIdx.x * blockDim.x + threadIdx.x;
  if (e >= NEDGES) return;
  const int u = edges[e];
  const int v = edges[NEDGES + e];
  if (winner[(size_t)u * NNODES + v] != e + 1) return;
  atomicAdd(&deg_lp[u], w_lp[e]);
  atomicAdd(&deg_hp[u], w_hp[e]);
}

// ---------------------------------------------------------------------------
// Pass C: inverse sqrt degrees (+1 for eye) + default diagonal values.
// adj_lp[i,i] = inv^2 (eye term); adj_hp[i,i] = 1 (mask=0 default).
// Self-loop winner edges override both in pass D.
// ---------------------------------------------------------------------------
__global__ __launch_bounds__(256) void node_inv_kernel(
    const float* __restrict__ deg_lp, const float* __restrict__ deg_hp,
    float* __restrict__ inv_lp, float* __restrict__ inv_hp,
    float* __restrict__ adj_lp, float* __restrict__ adj_hp) {
  const int i = blockIdx.x * blockDim.x + threadIdx.x;
  if (i >= NNODES) return;
  const float il = 1.0f / (sqrtf(deg_lp[i] + 1.0f) + EOS);
  const float ih = 1.0f / (sqrtf(deg_hp[i] + 1.0f) + EOS);
  inv_lp[i] = il;
  inv_hp[i] = ih;
  const size_t diag = (size_t)i * NNODES + i;
  adj_lp[diag] = il * il;
  adj_hp[diag] = 1.0f;
}

// ---------------------------------------------------------------------------
// Pass D: winner edges write normalized adjacency cells + unnorm=1.0.
// Race note: only the winner writes unnorm[cell]=1.0f; non-winner dup threads
// read either the winner id (!= their e+1) or 1.0f bits (1065353216 >
// NEDGES) — both correctly skip.
// ---------------------------------------------------------------------------
__global__ __launch_bounds__(256) void edge_write_kernel(
    const int* __restrict__ edges, const float* __restrict__ w_lp,
    const float* __restrict__ w_hp, const float* __restrict__ inv_lp,
    const float* __restrict__ inv_hp, float* __restrict__ adj_lp,
    float* __restrict__ adj_hp, float* __restrict__ unnorm) {
  const int e = blockIdx.x * blockDim.x + threadIdx.x;
  if (e >= NEDGES) return;
  const int u = edges[e];
  const int v = edges[NEDGES + e];
  const size_t cell = (size_t)u * NNODES + v;
  const int win = ((const int*)unnorm)[cell];
  if (win != e + 1) return;
  const float wl = w_lp[e];
  const float wh = w_hp[e];
  const float il = inv_lp[u] * inv_lp[v];
  const float ih = inv_hp[u] * inv_hp[v];
  if (u == v) {
    adj_lp[cell] = (wl + 1.0f) * il;
    adj_hp[cell] = 1.0f - (wh + 1.0f) * ih * ALPHA;
  } else {
    adj_lp[cell] = wl * il;
    adj_hp[cell] = -wh * ih * ALPHA;
  }
  unnorm[cell] = 1.0f;
}

extern "C" void kernel_launch(void* const* d_in, const int* in_sizes, int n_in,
                              void* d_out, int out_size, void* d_ws,
                              size_t ws_size, hipStream_t stream) {
  const float* feat  = (const float*)d_in[0];
  const int*   edges = (const int*)d_in[1];
  const float* w_emb = (const float*)d_in[2];
  const float* b_emb = (const float*)d_in[3];
  const float* w_mlp = (const float*)d_in[4];
  const float* b_mlp = (const float*)d_in[5];
  const float* noise = (const float*)d_in[6];

  float* out    = (float*)d_out;
  float* adj_lp = out;                 // [N,N]
  float* adj_hp = out + NN;            // [N,N]
  float* w_lp   = out + 2 * NN;        // [E]  (fully overwritten; not zeroed)
  float* w_hp   = w_lp + NEDGES;       // [E]  (fully overwritten; not zeroed)
  float* unnorm = w_hp + NEDGES;       // [N,N]  (doubles as winner array)

  float* deg_lp = (float*)d_ws;        // [N]
  float* deg_hp = deg_lp + NNODES;     // [N]
  float* inv_lp = deg_hp + NNODES;     // [N]
  float* inv_hp = inv_lp + NNODES;     // [N]
  float* g      = inv_hp + NNODES;     // [N]

  zero3_kernel<<<4096, 256, 0, stream>>>(
      (vfloat4*)adj_lp, (2 * NN) / 4, (vfloat4*)unnorm, NN / 4,
      (vfloat4*)deg_lp, (2 * NNODES) / 4);

  embed_g_kernel<<<NNODES / 4, 64, 0, stream>>>(feat, w_emb, b_emb, w_mlp,
                                                b_mlp, g);

  const int eb = (NEDGES + 255) / 256;
  edge_weights_kernel<<<eb, 256, 0, stream>>>(edges, g, noise, w_lp, w_hp,
                                              (int*)unnorm);
  edge_deg_kernel<<<eb, 256, 0, stream>>>(edges, w_lp, w_hp,
                                          (const int*)unnorm, deg_lp, deg_hp);
  node_inv_kernel<<<(NNODES + 255) / 256, 256, 0, stream>>>(
      deg_lp, deg_hp, inv_lp, inv_hp, adj_lp, adj_hp);
  edge_write_kernel<<<eb, 256, 0, stream>>>(edges, w_lp, w_hp, inv_lp, inv_hp,
                                            adj_lp, adj_hp, unnorm);
}